// Round 7
// baseline (556.580 us; speedup 1.0000x reference)
//
#include <hip/hip_runtime.h>
#include <hip/hip_bf16.h>
#include <math.h>
#include <stdint.h>

#define NN 2048
#define DD 512
#define EE 65536
#define EPSV 0.5f
#define SEN 2048  // covered-rank sentinel (= n in the reference)

static const size_t SZ = (size_t)NN * NN;  // 4,194,304

// ---------------------------------------------------------------------------
// Build dense adjacency (f32) + row sums + CSR degree, one edge pass.
// ---------------------------------------------------------------------------
__global__ __launch_bounds__(256) void build_adj(const int* __restrict__ row,
                                                 const int* __restrict__ col,
                                                 const float* __restrict__ attr,
                                                 float* __restrict__ adj,
                                                 float* __restrict__ rowsum,
                                                 int* __restrict__ degree) {
  int e = blockIdx.x * 256 + threadIdx.x;  // E exact multiple of 256
  float a = attr[e];
  int r = row[e];
  atomicAdd(&adj[r * NN + col[e]], a);
  atomicAdd(&rowsum[r], a);
  atomicAdd(&degree[r], 1);
}

// ---------------------------------------------------------------------------
// CSR scan: rows padded to multiple of 16 edges (filled with self-edges,
// exact: prop_min keeps self; OR to self idempotent).
// ---------------------------------------------------------------------------
__global__ __launch_bounds__(1024) void csr_scan(const int* __restrict__ degree,
                                                 int* __restrict__ row_ptr,
                                                 int* __restrict__ fill_ptr) {
  __shared__ int a[NN], b[NN];
  int t = threadIdx.x;
  for (int v = t; v < NN; v += 1024) a[v] = (degree[v] + 15) & ~15;  // pad16
  __syncthreads();
  int* src = a;
  int* dst = b;
  for (int off = 1; off < NN; off <<= 1) {  // Hillis-Steele inclusive scan
    for (int v = t; v < NN; v += 1024)
      dst[v] = src[v] + (v >= off ? src[v - off] : 0);
    __syncthreads();
    int* tmp = src; src = dst; dst = tmp;
  }
  for (int v = t; v < NN; v += 1024) {
    int pd = (degree[v] + 15) & ~15;
    int excl = src[v] - pd;
    row_ptr[v] = excl;
    fill_ptr[v] = excl;
  }
  if (t == 0) row_ptr[NN] = src[NN - 1];  // total padded edge count
}

__global__ __launch_bounds__(256) void csr_fill(const int* __restrict__ row,
                                                const int* __restrict__ col,
                                                int* __restrict__ fill_ptr,
                                                unsigned short* __restrict__ colidx) {
  int e = blockIdx.x * 256 + threadIdx.x;
  int pos = atomicAdd(&fill_ptr[row[e]], 1);
  colidx[pos] = (unsigned short)col[e];
}

__global__ __launch_bounds__(256) void csr_pad(const int* __restrict__ row_ptr,
                                               const int* __restrict__ degree,
                                               unsigned short* __restrict__ colidx) {
  int v = blockIdx.x * 256 + threadIdx.x;  // over NN
  int e0 = row_ptr[v] + degree[v], e1 = row_ptr[v + 1];
  for (int e = e0; e < e1; ++e) colidx[e] = (unsigned short)v;  // self-edges
}

// ---------------------------------------------------------------------------
// Greedy maximal k-independent set (k=2), single block, state in LDS.
// Round-6 gating + uint4 edge walks kept. Round-7: barrier diet — 8 barriers
// per round (was ~13): fold/mr-update/convergence fused via
// __syncthreads_count; snapshot passes halved by pre-writing tmp in the
// delta and fold phases. Semantics identical (hop snapshots preserved).
// ---------------------------------------------------------------------------
__global__ __launch_bounds__(1024) void mis_kernel(const int* __restrict__ row_ptr_g,
                                                   const unsigned short* __restrict__ colidx,
                                                   const int* __restrict__ rank_g,
                                                   int* __restrict__ mis_flag,
                                                   int* __restrict__ mis_list,
                                                   int* __restrict__ mis_count) {
  __shared__ int rank_s[NN];
  __shared__ int mr[NN];
  __shared__ int tmp[NN];
  __shared__ int cov[NN];
  __shared__ int dly[NN];
  __shared__ int mis_s[NN];
  __shared__ int row_ptr_s[NN + 1];
  __shared__ int cnt;
  int t = threadIdx.x;
  const uint4* col4 = (const uint4*)colidx;  // 8 u16 per uint4

  for (int v = t; v < NN; v += 1024) {
    int rk = rank_g[v];
    rank_s[v] = rk;
    mr[v] = rk;
    tmp[v] = rk;
    cov[v] = 0;
    mis_s[v] = 0;
    row_ptr_s[v] = row_ptr_g[v];
  }
  if (t == 0) {
    row_ptr_s[NN] = row_ptr_g[NN];
    cnt = 0;
  }
  __syncthreads();

#define WALK_MIN()                                                          \
  for (int v = t; v < NN; v += 1024) {                                      \
    int val = tmp[v];                                                       \
    if (val != SEN) {                                                       \
      int e0 = row_ptr_s[v];                                                \
      int nch = (row_ptr_s[v + 1] - e0) >> 3;                               \
      const uint4* b4 = col4 + (e0 >> 3);                                   \
      for (int c = 0; c < nch; c += 2) {                                    \
        uint4 A = b4[c], B = b4[c + 1];                                     \
        atomicMin(&mr[A.x & 0xFFFFu], val); atomicMin(&mr[A.x >> 16], val); \
        atomicMin(&mr[A.y & 0xFFFFu], val); atomicMin(&mr[A.y >> 16], val); \
        atomicMin(&mr[A.z & 0xFFFFu], val); atomicMin(&mr[A.z >> 16], val); \
        atomicMin(&mr[A.w & 0xFFFFu], val); atomicMin(&mr[A.w >> 16], val); \
        atomicMin(&mr[B.x & 0xFFFFu], val); atomicMin(&mr[B.x >> 16], val); \
        atomicMin(&mr[B.y & 0xFFFFu], val); atomicMin(&mr[B.y >> 16], val); \
        atomicMin(&mr[B.z & 0xFFFFu], val); atomicMin(&mr[B.z >> 16], val); \
        atomicMin(&mr[B.w & 0xFFFFu], val); atomicMin(&mr[B.w >> 16], val); \
      }                                                                     \
    }                                                                       \
  }

#define WALK_OR()                                                           \
  for (int v = t; v < NN; v += 1024) {                                      \
    if (tmp[v]) {                                                           \
      int e0 = row_ptr_s[v];                                                \
      int nch = (row_ptr_s[v + 1] - e0) >> 3;                               \
      const uint4* b4 = col4 + (e0 >> 3);                                   \
      for (int c = 0; c < nch; c += 2) {                                    \
        uint4 A = b4[c], B = b4[c + 1];                                     \
        dly[A.x & 0xFFFFu] = 1; dly[A.x >> 16] = 1;                         \
        dly[A.y & 0xFFFFu] = 1; dly[A.y >> 16] = 1;                         \
        dly[A.z & 0xFFFFu] = 1; dly[A.z >> 16] = 1;                         \
        dly[A.w & 0xFFFFu] = 1; dly[A.w >> 16] = 1;                         \
        dly[B.x & 0xFFFFu] = 1; dly[B.x >> 16] = 1;                         \
        dly[B.y & 0xFFFFu] = 1; dly[B.y >> 16] = 1;                         \
        dly[B.z & 0xFFFFu] = 1; dly[B.z >> 16] = 1;                         \
        dly[B.w & 0xFFFFu] = 1; dly[B.w >> 16] = 1;                         \
      }                                                                     \
    }                                                                       \
  }

  for (int round = 0; round < NN; ++round) {
    // A: min hop0 (tmp pre-snapshotted by init / previous fold phase)
    WALK_MIN();
    __syncthreads();
    // B: snapshot for hop1
    for (int v = t; v < NN; v += 1024) tmp[v] = mr[v];
    __syncthreads();
    // C: min hop1
    WALK_MIN();
    __syncthreads();
    // D: delta = newly selected; mis |= delta; prep OR hop0 sources
    for (int v = t; v < NN; v += 1024) {
      int nw = (rank_s[v] == mr[v]) ? 1 : 0;
      if (nw) mis_s[v] = 1;
      dly[v] = nw;
      tmp[v] = nw;
    }
    __syncthreads();
    // E: OR hop0
    WALK_OR();
    __syncthreads();
    // F: snapshot for hop1
    for (int v = t; v < NN; v += 1024) tmp[v] = dly[v];
    __syncthreads();
    // G: OR hop1
    WALK_OR();
    __syncthreads();
    // H: fold delta, reset mr for next round, fused convergence barrier
    int mypred = 0;
    for (int v = t; v < NN; v += 1024) {
      int cv = cov[v] | dly[v];
      cov[v] = cv;
      int nmr = cv ? SEN : rank_s[v];
      mr[v] = nmr;
      tmp[v] = nmr;
      mypred |= (cv == 0);
    }
    if (__syncthreads_count(mypred) == 0) break;
  }

  for (int v = t; v < NN; v += 1024) {
    mis_flag[v] = mis_s[v];
    if (mis_s[v]) mis_list[atomicAdd(&cnt, 1)] = v;  // unordered (consumers order-free)
  }
  __syncthreads();
  if (t == 0) *mis_count = cnt;
}

// ---------------------------------------------------------------------------
// adj -> rw in place: offdiag = 0.5*adj/s', diag = adj/s' + 0.5  (s'=s>0?s:1)
// ---------------------------------------------------------------------------
__global__ __launch_bounds__(256) void rw_transform(float* __restrict__ adj,
                                                    const float* __restrict__ rowsum) {
  int idx = blockIdx.x * 256 + threadIdx.x;
  int i = idx >> 11, j = idx & (NN - 1);
  float s = rowsum[i];
  s = (s > 0.f) ? s : 1.f;
  float v = adj[idx] / s;
  adj[idx] = (i == j) ? (v + EPSV) : (v * (1.f - EPSV));
}

// ---------------------------------------------------------------------------
// Gather the M MIS columns of rw into compact Bc[t][k] (row-major, k fast).
// ---------------------------------------------------------------------------
__global__ __launch_bounds__(256) void gather_cols(const float* __restrict__ rw,
                                                   const int* __restrict__ mis_list,
                                                   const int* __restrict__ mis_count,
                                                   float* __restrict__ Bc) {
  int total = (*mis_count) * NN;
  for (int idx = blockIdx.x * 256 + threadIdx.x; idx < total; idx += gridDim.x * 256) {
    int tcol = idx >> 11, k = idx & (NN - 1);
    Bc[idx] = rw[(size_t)k * NN + mis_list[tcol]];
  }
}

// ---------------------------------------------------------------------------
// c2 + Gumbel-argmax as a single-owner skinny GEMM.
// Grid 128 x (16 rows); thread (row_local = t>>4, cg = t&15) owns 1 row and
// 4 columns per 64-col tile. Streams k in float4 chunks: 1 A-load (shared by
// the 16 col-threads of the row -> coalesces to one tx) + 4 independent
// B-streams (L2-hot Bc). A is read ONCE total (16 MB) vs M x 16 MB before.
// Row is block-exclusive -> per-row argmax via shfl reduction, direct
// cluster write (no packed buffer / decode pass). Tie + sentinel semantics
// identical to prior rounds (u64 key, low bits 2047-m, 0 => cluster 0).
// ---------------------------------------------------------------------------
__device__ inline unsigned int f32_key(float x) {
  unsigned int u = __float_as_uint(x);
  return (u & 0x80000000u) ? ~u : (u | 0x80000000u);
}
__device__ inline float dot4(float4 a, float4 b) {
  return ((a.x * b.x + a.y * b.y) + (a.z * b.z + a.w * b.w));
}
__device__ inline unsigned long long umax64(unsigned long long a, unsigned long long b) {
  return a > b ? a : b;
}

__global__ __launch_bounds__(256) void c2_gemm_argmax(const float* __restrict__ rw,
                                                      const float* __restrict__ Bc,
                                                      const float* __restrict__ u,
                                                      const int* __restrict__ mis_list,
                                                      const int* __restrict__ mis_count,
                                                      int* __restrict__ cluster,
                                                      int* __restrict__ counts) {
  int M = *mis_count;
  int t = threadIdx.x;
  int row_local = t >> 4;  // 0..15
  int cg = t & 15;         // 0..15
  int row = blockIdx.x * 16 + row_local;
  const float4* Arow = (const float4*)(rw + (size_t)row * NN);
  unsigned long long best = 0ull;

  int ntiles = (M + 63) >> 6;
  for (int ct = 0; ct < ntiles; ++ct) {
    int c0 = ct * 64 + cg * 4;
    const float4* B0 = (const float4*)(Bc + (size_t)(c0 + 0) * NN);
    const float4* B1 = (const float4*)(Bc + (size_t)(c0 + 1) * NN);
    const float4* B2 = (const float4*)(Bc + (size_t)(c0 + 2) * NN);
    const float4* B3 = (const float4*)(Bc + (size_t)(c0 + 3) * NN);
    float acc0 = 0.f, acc1 = 0.f, acc2 = 0.f, acc3 = 0.f;
#pragma unroll 4
    for (int kc = 0; kc < NN / 4; ++kc) {
      float4 a = Arow[kc];
      float4 b0 = B0[kc], b1 = B1[kc], b2 = B2[kc], b3 = B3[kc];
      acc0 += dot4(a, b0);
      acc1 += dot4(a, b1);
      acc2 += dot4(a, b2);
      acc3 += dot4(a, b3);
    }
    float accs[4] = {acc0, acc1, acc2, acc3};
#pragma unroll
    for (int j = 0; j < 4; ++j) {
      int colv = c0 + j;
      if (colv < M) {
        float s = accs[j];
        if (s > 0.f) {
          int m = mis_list[colv];
          float uu = u[(size_t)row * NN + m];
          float g = -logf(-logf(uu + 1e-20f) + 1e-20f);
          float logit = logf(s) + g;
          unsigned long long key =
              ((unsigned long long)f32_key(logit) << 32) | (unsigned int)(NN - 1 - m);
          best = umax64(best, key);
        }
      }
    }
  }
  // reduce across the 16 col-threads of this row (lanes are 16-aligned)
  best = umax64(best, __shfl_xor(best, 1));
  best = umax64(best, __shfl_xor(best, 2));
  best = umax64(best, __shfl_xor(best, 4));
  best = umax64(best, __shfl_xor(best, 8));
  if (cg == 0) {
    int m = (best == 0ull) ? 0 : (NN - 1 - (int)(best & 0xFFFFFFFFull));
    cluster[row] = m;
    atomicAdd(&counts[m], 1);
  }
}

// ---------------------------------------------------------------------------
__global__ __launch_bounds__(256) void adjc_scatter(const int* __restrict__ row,
                                                    const int* __restrict__ col,
                                                    const float* __restrict__ attr,
                                                    const int* __restrict__ cluster,
                                                    float* __restrict__ adjc) {
  int e = blockIdx.x * 256 + threadIdx.x;
  int cr = cluster[row[e]], cc = cluster[col[e]];
  atomicAdd(&adjc[(size_t)cr * NN + cc], attr[e]);
}

// ---------------------------------------------------------------------------
// c_hard, p_inv, and (folded) mis outputs.
// ---------------------------------------------------------------------------
__global__ __launch_bounds__(256) void write_chpm(const int* __restrict__ cluster,
                                                  const int* __restrict__ counts,
                                                  const int* __restrict__ mis_flag,
                                                  float* __restrict__ out_ch,
                                                  float* __restrict__ out_pinv,
                                                  float* __restrict__ out_mis) {
  int idx = blockIdx.x * 256 + threadIdx.x;  // over N*N
  int a = idx >> 11, b = idx & (NN - 1);
  out_ch[idx] = (cluster[a] == b) ? 1.f : 0.f;
  float pv = 0.f;
  if (cluster[b] == a) {
    int c = counts[a];
    pv = 1.f / (float)(c > 0 ? c : 1);
  }
  out_pinv[idx] = pv;
  if (idx < NN) out_mis[idx] = mis_flag[idx] ? 1.f : 0.f;
}

// ---------------------------------------------------------------------------
__global__ __launch_bounds__(256) void xpool_scatter(const float* __restrict__ x,
                                                     const int* __restrict__ cluster,
                                                     float* __restrict__ xp) {
  int idx = blockIdx.x * 256 + threadIdx.x;  // over N*D
  int i = idx >> 9;
  atomicAdd(&xp[cluster[i] * DD + (idx & (DD - 1))], x[idx]);
}

__global__ __launch_bounds__(256) void xpool_scale(float* __restrict__ xp,
                                                   const int* __restrict__ counts) {
  int idx = blockIdx.x * 256 + threadIdx.x;
  int c = counts[idx >> 9];
  xp[idx] = xp[idx] / (float)(c > 0 ? c : 1);
}

// ---------------------------------------------------------------------------
extern "C" void kernel_launch(void* const* d_in, const int* in_sizes, int n_in,
                              void* d_out, int out_size, void* d_ws, size_t ws_size,
                              hipStream_t stream) {
  const int*   edge_index = (const int*)d_in[0];
  const float* edge_attr  = (const float*)d_in[1];
  const float* x          = (const float*)d_in[2];
  const int*   rank       = (const int*)d_in[3];
  const float* u          = (const float*)d_in[4];
  float* out              = (float*)d_out;  // f32 outputs, concatenated

  const int* row = edge_index;
  const int* col = edge_index + EE;

  float* out_adjc = out;                 // N*N — doubles as adj/rw scratch
  float* out_ch   = out + SZ;            // N*N — doubles as Bc scratch
  float* out_pinv = out + 2 * SZ;        // N*N
  float* out_mis  = out + 3 * SZ;        // N
  float* out_xp   = out + 3 * SZ + NN;   // N*D

  // d_ws layout (~270 KB). First 3 arrays need zeroing; rest fully written.
  float* rowsum    = (float*)d_ws;                 // N  (zeroed)
  int*   counts    = (int*)(rowsum + NN);          // N  (zeroed)
  int*   degree    = counts + NN;                  // N  (zeroed)
  int*   mis_flag  = degree + NN;                  // N
  int*   cluster   = mis_flag + NN;                // N
  int*   mis_list  = cluster + NN;                 // N
  int*   mis_count = mis_list + NN;                // 1
  int*   fill_ptr  = mis_count + 1;                // N
  int*   row_ptr   = fill_ptr + NN;                // N+1
  unsigned short* colidx =                          // padded E (<=98304) u16, 32B-aligned
      (unsigned short*)(((uintptr_t)(row_ptr + NN + 1) + 31) & ~(uintptr_t)31);

  hipMemsetAsync(out_adjc, 0, SZ * sizeof(float), stream);
  hipMemsetAsync(out_xp, 0, (size_t)NN * DD * sizeof(float), stream);
  hipMemsetAsync(d_ws, 0, 3 * NN * sizeof(int), stream);

  build_adj<<<EE / 256, 256, 0, stream>>>(row, col, edge_attr, out_adjc, rowsum, degree);
  csr_scan<<<1, 1024, 0, stream>>>(degree, row_ptr, fill_ptr);
  csr_fill<<<EE / 256, 256, 0, stream>>>(row, col, fill_ptr, colidx);
  csr_pad<<<NN / 256, 256, 0, stream>>>(row_ptr, degree, colidx);
  mis_kernel<<<1, 1024, 0, stream>>>(row_ptr, colidx, rank, mis_flag, mis_list, mis_count);
  rw_transform<<<(NN * NN) / 256, 256, 0, stream>>>(out_adjc, rowsum);
  gather_cols<<<256, 256, 0, stream>>>(out_adjc, mis_list, mis_count, out_ch);
  c2_gemm_argmax<<<NN / 16, 256, 0, stream>>>(out_adjc, out_ch, u, mis_list, mis_count,
                                              cluster, counts);

  // rw no longer needed: rewrite the region with the real adj_c
  hipMemsetAsync(out_adjc, 0, SZ * sizeof(float), stream);
  adjc_scatter<<<EE / 256, 256, 0, stream>>>(row, col, edge_attr, cluster, out_adjc);

  write_chpm<<<(NN * NN) / 256, 256, 0, stream>>>(cluster, counts, mis_flag,
                                                  out_ch, out_pinv, out_mis);
  xpool_scatter<<<(NN * DD) / 256, 256, 0, stream>>>(x, cluster, out_xp);
  xpool_scale<<<(NN * DD) / 256, 256, 0, stream>>>(out_xp, counts);
}

// Round 8
// 299.100 us; speedup vs baseline: 1.8608x; 1.8608x over previous
//
#include <hip/hip_runtime.h>
#include <hip/hip_bf16.h>
#include <math.h>
#include <stdint.h>

#define NN 2048
#define DD 512
#define EE 65536
#define EPSV 0.5f
#define SEN 2048  // covered-rank sentinel (= n in the reference)

static const size_t SZ = (size_t)NN * NN;  // 4,194,304

// ---------------------------------------------------------------------------
// Build dense adjacency (f32) + row sums + CSR degree, one edge pass.
// ---------------------------------------------------------------------------
__global__ __launch_bounds__(256) void build_adj(const int* __restrict__ row,
                                                 const int* __restrict__ col,
                                                 const float* __restrict__ attr,
                                                 float* __restrict__ adj,
                                                 float* __restrict__ rowsum,
                                                 int* __restrict__ degree) {
  int e = blockIdx.x * 256 + threadIdx.x;  // E exact multiple of 256
  float a = attr[e];
  int r = row[e];
  atomicAdd(&adj[r * NN + col[e]], a);
  atomicAdd(&rowsum[r], a);
  atomicAdd(&degree[r], 1);
}

// ---------------------------------------------------------------------------
// CSR scan + self-edge padding fused (single block). Rows padded to a
// multiple of 16 edges with self-edges (exact: prop_min keeps self; OR to
// self idempotent). Pad region [rp+deg, rp_next) is disjoint from the
// atomic-fill region [rp, rp+deg), so csr_fill can run after.
// ---------------------------------------------------------------------------
__global__ __launch_bounds__(1024) void csr_scan_pad(const int* __restrict__ degree,
                                                     int* __restrict__ row_ptr,
                                                     int* __restrict__ fill_ptr,
                                                     unsigned short* __restrict__ colidx) {
  __shared__ int a[NN], b[NN];
  int t = threadIdx.x;
  for (int v = t; v < NN; v += 1024) a[v] = (degree[v] + 15) & ~15;  // pad16
  __syncthreads();
  int* src = a;
  int* dst = b;
  for (int off = 1; off < NN; off <<= 1) {  // Hillis-Steele inclusive scan
    for (int v = t; v < NN; v += 1024)
      dst[v] = src[v] + (v >= off ? src[v - off] : 0);
    __syncthreads();
    int* tmp = src; src = dst; dst = tmp;
  }
  for (int v = t; v < NN; v += 1024) {
    int dg = degree[v];
    int pd = (dg + 15) & ~15;
    int end = src[v];
    int excl = end - pd;
    row_ptr[v] = excl;
    fill_ptr[v] = excl;
    for (int e = excl + dg; e < end; ++e) colidx[e] = (unsigned short)v;  // self pad
  }
  if (t == 0) row_ptr[NN] = src[NN - 1];  // total padded edge count
}

__global__ __launch_bounds__(256) void csr_fill(const int* __restrict__ row,
                                                const int* __restrict__ col,
                                                int* __restrict__ fill_ptr,
                                                unsigned short* __restrict__ colidx) {
  int e = blockIdx.x * 256 + threadIdx.x;
  int pos = atomicAdd(&fill_ptr[row[e]], 1);
  colidx[pos] = (unsigned short)col[e];
}

// ---------------------------------------------------------------------------
// Greedy maximal k-independent set (k=2), single block, state in LDS.
// Gating + uint4 edge walks + 8-barrier round structure (round 7). Also
// emits misinv[v] = compact MIS slot (or -1) for the fused gather.
// ---------------------------------------------------------------------------
__global__ __launch_bounds__(1024) void mis_kernel(const int* __restrict__ row_ptr_g,
                                                   const unsigned short* __restrict__ colidx,
                                                   const int* __restrict__ rank_g,
                                                   int* __restrict__ mis_flag,
                                                   int* __restrict__ mis_list,
                                                   int* __restrict__ misinv,
                                                   int* __restrict__ mis_count) {
  __shared__ int rank_s[NN];
  __shared__ int mr[NN];
  __shared__ int tmp[NN];
  __shared__ int cov[NN];
  __shared__ int dly[NN];
  __shared__ int mis_s[NN];
  __shared__ int row_ptr_s[NN + 1];
  __shared__ int cnt;
  int t = threadIdx.x;
  const uint4* col4 = (const uint4*)colidx;  // 8 u16 per uint4

  for (int v = t; v < NN; v += 1024) {
    int rk = rank_g[v];
    rank_s[v] = rk;
    mr[v] = rk;
    tmp[v] = rk;
    cov[v] = 0;
    mis_s[v] = 0;
    row_ptr_s[v] = row_ptr_g[v];
  }
  if (t == 0) {
    row_ptr_s[NN] = row_ptr_g[NN];
    cnt = 0;
  }
  __syncthreads();

#define WALK_MIN()                                                          \
  for (int v = t; v < NN; v += 1024) {                                      \
    int val = tmp[v];                                                       \
    if (val != SEN) {                                                       \
      int e0 = row_ptr_s[v];                                                \
      int nch = (row_ptr_s[v + 1] - e0) >> 3;                               \
      const uint4* b4 = col4 + (e0 >> 3);                                   \
      for (int c = 0; c < nch; c += 2) {                                    \
        uint4 A = b4[c], B = b4[c + 1];                                     \
        atomicMin(&mr[A.x & 0xFFFFu], val); atomicMin(&mr[A.x >> 16], val); \
        atomicMin(&mr[A.y & 0xFFFFu], val); atomicMin(&mr[A.y >> 16], val); \
        atomicMin(&mr[A.z & 0xFFFFu], val); atomicMin(&mr[A.z >> 16], val); \
        atomicMin(&mr[A.w & 0xFFFFu], val); atomicMin(&mr[A.w >> 16], val); \
        atomicMin(&mr[B.x & 0xFFFFu], val); atomicMin(&mr[B.x >> 16], val); \
        atomicMin(&mr[B.y & 0xFFFFu], val); atomicMin(&mr[B.y >> 16], val); \
        atomicMin(&mr[B.z & 0xFFFFu], val); atomicMin(&mr[B.z >> 16], val); \
        atomicMin(&mr[B.w & 0xFFFFu], val); atomicMin(&mr[B.w >> 16], val); \
      }                                                                     \
    }                                                                       \
  }

#define WALK_OR()                                                           \
  for (int v = t; v < NN; v += 1024) {                                      \
    if (tmp[v]) {                                                           \
      int e0 = row_ptr_s[v];                                                \
      int nch = (row_ptr_s[v + 1] - e0) >> 3;                               \
      const uint4* b4 = col4 + (e0 >> 3);                                   \
      for (int c = 0; c < nch; c += 2) {                                    \
        uint4 A = b4[c], B = b4[c + 1];                                     \
        dly[A.x & 0xFFFFu] = 1; dly[A.x >> 16] = 1;                         \
        dly[A.y & 0xFFFFu] = 1; dly[A.y >> 16] = 1;                         \
        dly[A.z & 0xFFFFu] = 1; dly[A.z >> 16] = 1;                         \
        dly[A.w & 0xFFFFu] = 1; dly[A.w >> 16] = 1;                         \
        dly[B.x & 0xFFFFu] = 1; dly[B.x >> 16] = 1;                         \
        dly[B.y & 0xFFFFu] = 1; dly[B.y >> 16] = 1;                         \
        dly[B.z & 0xFFFFu] = 1; dly[B.z >> 16] = 1;                         \
        dly[B.w & 0xFFFFu] = 1; dly[B.w >> 16] = 1;                         \
      }                                                                     \
    }                                                                       \
  }

  for (int round = 0; round < NN; ++round) {
    WALK_MIN();                                                  // min hop0
    __syncthreads();
    for (int v = t; v < NN; v += 1024) tmp[v] = mr[v];           // snapshot
    __syncthreads();
    WALK_MIN();                                                  // min hop1
    __syncthreads();
    for (int v = t; v < NN; v += 1024) {                         // delta
      int nw = (rank_s[v] == mr[v]) ? 1 : 0;
      if (nw) mis_s[v] = 1;
      dly[v] = nw;
      tmp[v] = nw;
    }
    __syncthreads();
    WALK_OR();                                                   // OR hop0
    __syncthreads();
    for (int v = t; v < NN; v += 1024) tmp[v] = dly[v];          // snapshot
    __syncthreads();
    WALK_OR();                                                   // OR hop1
    __syncthreads();
    int mypred = 0;                                              // fold+conv
    for (int v = t; v < NN; v += 1024) {
      int cv = cov[v] | dly[v];
      cov[v] = cv;
      int nmr = cv ? SEN : rank_s[v];
      mr[v] = nmr;
      tmp[v] = nmr;
      mypred |= (cv == 0);
    }
    if (__syncthreads_count(mypred) == 0) break;
  }

  for (int v = t; v < NN; v += 1024) {
    int s = mis_s[v];
    mis_flag[v] = s;
    int slot = -1;
    if (s) {
      slot = atomicAdd(&cnt, 1);  // unordered: all consumers order-free
      mis_list[slot] = v;
    }
    misinv[v] = slot;
  }
  __syncthreads();
  if (t == 0) *mis_count = cnt;
}

// ---------------------------------------------------------------------------
// adj -> rw in place, fused with MIS-column gather into compact Bc:
// Bc[misinv[j]][i] = rw[i][j] for MIS columns j.
// ---------------------------------------------------------------------------
__global__ __launch_bounds__(256) void rw_transform_gather(float* __restrict__ adj,
                                                           const float* __restrict__ rowsum,
                                                           const int* __restrict__ misinv,
                                                           float* __restrict__ Bc) {
  int idx = blockIdx.x * 256 + threadIdx.x;  // over N*N
  int i = idx >> 11, j = idx & (NN - 1);
  float s = rowsum[i];
  s = (s > 0.f) ? s : 1.f;
  float v = adj[idx] / s;
  v = (i == j) ? (v + EPSV) : (v * (1.f - EPSV));
  adj[idx] = v;
  int tc = misinv[j];
  if (tc >= 0) Bc[(size_t)tc * NN + i] = v;
}

// ---------------------------------------------------------------------------
// Fused c2 + Gumbel-argmax, 4 columns per job (round-6 structure, A-traffic
// /4). Job = (col-group of 4, 32-row tile). Each lane register-caches its
// slice of 4 compact columns (4 x 8 float4); rows streamed as 8 coalesced
// independent float4 loads. Deterministic shuffle tree per column. Winner
// folded via u64 atomicMax: key = mono(logit)<<32 | (2047-m) -> np.argmax
// first-occurrence ties; sentinel 0 row -> cluster 0.
// ---------------------------------------------------------------------------
__device__ inline unsigned int f32_key(float x) {
  unsigned int u = __float_as_uint(x);
  return (u & 0x80000000u) ? ~u : (u | 0x80000000u);
}
__device__ inline float dot4(float4 a, float4 b) {
  return ((a.x * b.x + a.y * b.y) + (a.z * b.z + a.w * b.w));
}
__device__ inline unsigned long long umax64(unsigned long long a, unsigned long long b) {
  return a > b ? a : b;
}

__global__ __launch_bounds__(256) void c2_argmax(const float* __restrict__ rw,
                                                 const float* __restrict__ Bc,
                                                 const float* __restrict__ u,
                                                 const int* __restrict__ mis_list,
                                                 const int* __restrict__ mis_count,
                                                 unsigned long long* __restrict__ packed) {
  int M = *mis_count;
  int ncg = (M + 3) >> 2;
  int njobs = ncg * 64;  // 64 tiles of 32 rows
  int lane = threadIdx.x & 63, w = threadIdx.x >> 6;
  for (int j = blockIdx.x; j < njobs; j += gridDim.x) {
    int cg = j >> 6, tile = j & 63;
    int c0 = cg * 4;
    float4 creg[4][8];
    int mcol[4];
#pragma unroll
    for (int cc = 0; cc < 4; ++cc) {
      int colv = c0 + cc;
      int cl = colv < M ? colv : (M - 1);
      mcol[cc] = mis_list[cl];
      const float4* cb = (const float4*)(Bc + (size_t)cl * NN);
#pragma unroll
      for (int q = 0; q < 8; ++q) creg[cc][q] = cb[q * 64 + lane];
    }
    int rbase = tile * 32 + w * 8;
#pragma unroll
    for (int it = 0; it < 8; ++it) {
      int r = rbase + it;
      const float4* rp = (const float4*)(rw + (size_t)r * NN);
      float4 a0 = rp[lane], a1 = rp[64 + lane], a2 = rp[128 + lane], a3 = rp[192 + lane];
      float4 a4 = rp[256 + lane], a5 = rp[320 + lane], a6 = rp[384 + lane], a7 = rp[448 + lane];
      float sacc[4];
#pragma unroll
      for (int cc = 0; cc < 4; ++cc) {
        float s01 = dot4(a0, creg[cc][0]) + dot4(a1, creg[cc][1]);
        float s23 = dot4(a2, creg[cc][2]) + dot4(a3, creg[cc][3]);
        float s45 = dot4(a4, creg[cc][4]) + dot4(a5, creg[cc][5]);
        float s67 = dot4(a6, creg[cc][6]) + dot4(a7, creg[cc][7]);
        float s = (s01 + s23) + (s45 + s67);
        s += __shfl_xor(s, 32);
        s += __shfl_xor(s, 16);
        s += __shfl_xor(s, 8);
        s += __shfl_xor(s, 4);
        s += __shfl_xor(s, 2);
        s += __shfl_xor(s, 1);
        sacc[cc] = s;
      }
      if (lane == 0) {
        unsigned long long best = 0ull;
#pragma unroll
        for (int cc = 0; cc < 4; ++cc) {
          if (c0 + cc < M && sacc[cc] > 0.f) {
            int m = mcol[cc];
            float uu = u[(size_t)r * NN + m];
            float g = -logf(-logf(uu + 1e-20f) + 1e-20f);
            float logit = logf(sacc[cc]) + g;
            unsigned long long key =
                ((unsigned long long)f32_key(logit) << 32) | (unsigned int)(NN - 1 - m);
            best = umax64(best, key);
          }
        }
        if (best) atomicMax(&packed[r], best);
      }
    }
  }
}

// ---------------------------------------------------------------------------
__global__ __launch_bounds__(256) void cluster_decode(const unsigned long long* __restrict__ packed,
                                                      int* __restrict__ cluster,
                                                      int* __restrict__ counts) {
  int i = blockIdx.x * 256 + threadIdx.x;
  unsigned long long p = packed[i];
  int m = (p == 0ull) ? 0 : (NN - 1 - (int)(p & 0xFFFFFFFFull));
  cluster[i] = m;
  atomicAdd(&counts[m], 1);
}

// ---------------------------------------------------------------------------
__global__ __launch_bounds__(256) void adjc_scatter(const int* __restrict__ row,
                                                    const int* __restrict__ col,
                                                    const float* __restrict__ attr,
                                                    const int* __restrict__ cluster,
                                                    float* __restrict__ adjc) {
  int e = blockIdx.x * 256 + threadIdx.x;
  int cr = cluster[row[e]], cc = cluster[col[e]];
  atomicAdd(&adjc[(size_t)cr * NN + cc], attr[e]);
}

// ---------------------------------------------------------------------------
__global__ __launch_bounds__(256) void xpool_scatter(const float* __restrict__ x,
                                                     const int* __restrict__ cluster,
                                                     float* __restrict__ xp) {
  int idx = blockIdx.x * 256 + threadIdx.x;  // over N*D
  int i = idx >> 9;
  atomicAdd(&xp[cluster[i] * DD + (idx & (DD - 1))], x[idx]);
}

// ---------------------------------------------------------------------------
// c_hard, p_inv, mis, and x_pool scaling in one pass (runs after all
// accumulators are final; same-stream ordering guarantees).
// ---------------------------------------------------------------------------
__global__ __launch_bounds__(256) void write_chpm(const int* __restrict__ cluster,
                                                  const int* __restrict__ counts,
                                                  const int* __restrict__ mis_flag,
                                                  float* __restrict__ out_ch,
                                                  float* __restrict__ out_pinv,
                                                  float* __restrict__ out_mis,
                                                  float* __restrict__ out_xp) {
  int idx = blockIdx.x * 256 + threadIdx.x;  // over N*N
  int a = idx >> 11, b = idx & (NN - 1);
  out_ch[idx] = (cluster[a] == b) ? 1.f : 0.f;
  float pv = 0.f;
  if (cluster[b] == a) {
    int c = counts[a];
    pv = 1.f / (float)(c > 0 ? c : 1);
  }
  out_pinv[idx] = pv;
  if (idx < NN) out_mis[idx] = mis_flag[idx] ? 1.f : 0.f;
  if (idx < NN * DD) {
    int c = counts[idx >> 9];
    out_xp[idx] = out_xp[idx] / (float)(c > 0 ? c : 1);
  }
}

// ---------------------------------------------------------------------------
extern "C" void kernel_launch(void* const* d_in, const int* in_sizes, int n_in,
                              void* d_out, int out_size, void* d_ws, size_t ws_size,
                              hipStream_t stream) {
  const int*   edge_index = (const int*)d_in[0];
  const float* edge_attr  = (const float*)d_in[1];
  const float* x          = (const float*)d_in[2];
  const int*   rank       = (const int*)d_in[3];
  const float* u          = (const float*)d_in[4];
  float* out              = (float*)d_out;  // f32 outputs, concatenated

  const int* row = edge_index;
  const int* col = edge_index + EE;

  float* out_adjc = out;                 // N*N — doubles as adj/rw scratch
  float* out_ch   = out + SZ;            // N*N — doubles as Bc scratch
  float* out_pinv = out + 2 * SZ;        // N*N
  float* out_mis  = out + 3 * SZ;        // N
  float* out_xp   = out + 3 * SZ + NN;   // N*D

  // d_ws layout (~290 KB). First 4 arrays zeroed; rest fully written.
  unsigned long long* packed = (unsigned long long*)d_ws;  // N u64 (zeroed)
  float* rowsum    = (float*)(packed + NN);        // N  (zeroed)
  int*   counts    = (int*)(rowsum + NN);          // N  (zeroed)
  int*   degree    = counts + NN;                  // N  (zeroed)
  int*   mis_flag  = degree + NN;                  // N
  int*   cluster   = mis_flag + NN;                // N
  int*   mis_list  = cluster + NN;                 // N
  int*   misinv    = mis_list + NN;                // N
  int*   mis_count = misinv + NN;                  // 1
  int*   fill_ptr  = mis_count + 1;                // N
  int*   row_ptr   = fill_ptr + NN;                // N+1
  unsigned short* colidx =                          // padded E (<=98304) u16, 32B-aligned
      (unsigned short*)(((uintptr_t)(row_ptr + NN + 1) + 31) & ~(uintptr_t)31);

  hipMemsetAsync(out_adjc, 0, SZ * sizeof(float), stream);
  hipMemsetAsync(out_xp, 0, (size_t)NN * DD * sizeof(float), stream);
  hipMemsetAsync(d_ws, 0, NN * sizeof(unsigned long long) + 3 * NN * sizeof(int), stream);

  build_adj<<<EE / 256, 256, 0, stream>>>(row, col, edge_attr, out_adjc, rowsum, degree);
  csr_scan_pad<<<1, 1024, 0, stream>>>(degree, row_ptr, fill_ptr, colidx);
  csr_fill<<<EE / 256, 256, 0, stream>>>(row, col, fill_ptr, colidx);
  mis_kernel<<<1, 1024, 0, stream>>>(row_ptr, colidx, rank, mis_flag, mis_list, misinv,
                                     mis_count);
  rw_transform_gather<<<(NN * NN) / 256, 256, 0, stream>>>(out_adjc, rowsum, misinv, out_ch);
  c2_argmax<<<1024, 256, 0, stream>>>(out_adjc, out_ch, u, mis_list, mis_count, packed);
  cluster_decode<<<NN / 256, 256, 0, stream>>>(packed, cluster, counts);

  // rw no longer needed: rewrite the region with the real adj_c
  hipMemsetAsync(out_adjc, 0, SZ * sizeof(float), stream);
  adjc_scatter<<<EE / 256, 256, 0, stream>>>(row, col, edge_attr, cluster, out_adjc);
  xpool_scatter<<<(NN * DD) / 256, 256, 0, stream>>>(x, cluster, out_xp);

  write_chpm<<<(NN * NN) / 256, 256, 0, stream>>>(cluster, counts, mis_flag,
                                                  out_ch, out_pinv, out_mis, out_xp);
}

// Round 9
// 292.160 us; speedup vs baseline: 1.9051x; 1.0238x over previous
//
#include <hip/hip_runtime.h>
#include <hip/hip_bf16.h>
#include <math.h>
#include <stdint.h>

#define NN 2048
#define DD 512
#define EE 65536
#define EPSV 0.5f
#define SEN 2048  // covered-rank sentinel (= n in the reference)

static const size_t SZ = (size_t)NN * NN;  // 4,194,304

// ---------------------------------------------------------------------------
// Build dense adjacency (f32) + row sums + CSR/CSC degrees, one edge pass.
// ---------------------------------------------------------------------------
__global__ __launch_bounds__(256) void build_adj(const int* __restrict__ row,
                                                 const int* __restrict__ col,
                                                 const float* __restrict__ attr,
                                                 float* __restrict__ adj,
                                                 float* __restrict__ rowsum,
                                                 int* __restrict__ degree,
                                                 int* __restrict__ cdeg) {
  int e = blockIdx.x * 256 + threadIdx.x;  // E exact multiple of 256
  float a = attr[e];
  int r = row[e], c = col[e];
  atomicAdd(&adj[r * NN + c], a);
  atomicAdd(&rowsum[r], a);
  atomicAdd(&degree[r], 1);
  atomicAdd(&cdeg[c], 1);
}

// ---------------------------------------------------------------------------
// Dual CSR/CSC scan + self-edge padding (single block). Rows padded to a
// multiple of 16 with self-edges (exact: prop_min keeps self; OR idempotent).
// ---------------------------------------------------------------------------
__global__ __launch_bounds__(1024) void csr_scan_pad(const int* __restrict__ degree,
                                                     const int* __restrict__ cdeg,
                                                     int* __restrict__ row_ptr,
                                                     int* __restrict__ fill_ptr,
                                                     int* __restrict__ col_ptr,
                                                     int* __restrict__ cfill_ptr,
                                                     unsigned short* __restrict__ colidx,
                                                     unsigned short* __restrict__ rowidx) {
  __shared__ int a[NN], b[NN];
  int t = threadIdx.x;
  // ---- CSR (out-edges keyed by row) ----
  for (int v = t; v < NN; v += 1024) a[v] = (degree[v] + 15) & ~15;
  __syncthreads();
  int* src = a; int* dst = b;
  for (int off = 1; off < NN; off <<= 1) {
    for (int v = t; v < NN; v += 1024) dst[v] = src[v] + (v >= off ? src[v - off] : 0);
    __syncthreads();
    int* tp = src; src = dst; dst = tp;
  }
  for (int v = t; v < NN; v += 1024) {
    int dg = degree[v];
    int end = src[v];
    int excl = end - ((dg + 15) & ~15);
    row_ptr[v] = excl;
    fill_ptr[v] = excl;
    for (int e = excl + dg; e < end; ++e) colidx[e] = (unsigned short)v;  // self pad
  }
  if (t == 0) row_ptr[NN] = src[NN - 1];
  __syncthreads();
  // ---- CSC (in-edges keyed by col) ----
  for (int v = t; v < NN; v += 1024) a[v] = (cdeg[v] + 15) & ~15;
  __syncthreads();
  src = a; dst = b;
  for (int off = 1; off < NN; off <<= 1) {
    for (int v = t; v < NN; v += 1024) dst[v] = src[v] + (v >= off ? src[v - off] : 0);
    __syncthreads();
    int* tp = src; src = dst; dst = tp;
  }
  for (int v = t; v < NN; v += 1024) {
    int dg = cdeg[v];
    int end = src[v];
    int excl = end - ((dg + 15) & ~15);
    col_ptr[v] = excl;
    cfill_ptr[v] = excl;
    for (int e = excl + dg; e < end; ++e) rowidx[e] = (unsigned short)v;  // self pad
  }
  if (t == 0) col_ptr[NN] = src[NN - 1];
}

__global__ __launch_bounds__(256) void csr_fill(const int* __restrict__ row,
                                                const int* __restrict__ col,
                                                int* __restrict__ fill_ptr,
                                                int* __restrict__ cfill_ptr,
                                                unsigned short* __restrict__ colidx,
                                                unsigned short* __restrict__ rowidx) {
  int e = blockIdx.x * 256 + threadIdx.x;
  int r = row[e], c = col[e];
  colidx[atomicAdd(&fill_ptr[r], 1)] = (unsigned short)c;
  rowidx[atomicAdd(&cfill_ptr[c], 1)] = (unsigned short)r;
}

// ---------------------------------------------------------------------------
// Greedy maximal k-independent set (k=2), single block, state in LDS.
// Round-9 change: min hop 1 is a GATHER at uncovered destinations over the
// CSC in-edge list (exact: covered nodes can never satisfy rank==mr since
// their own rank is neither SEN nor any uncovered rank, and mr is reset each
// round). Hop-1 LDS work drops from ~96K edges/round to ~47*U.
// ---------------------------------------------------------------------------
__global__ __launch_bounds__(1024) void mis_kernel(const int* __restrict__ row_ptr_g,
                                                   const int* __restrict__ col_ptr_g,
                                                   const unsigned short* __restrict__ colidx,
                                                   const unsigned short* __restrict__ rowidx,
                                                   const int* __restrict__ rank_g,
                                                   int* __restrict__ mis_flag,
                                                   int* __restrict__ mis_list,
                                                   int* __restrict__ misinv,
                                                   int* __restrict__ mis_count) {
  __shared__ int rank_s[NN];
  __shared__ int mr[NN];
  __shared__ int tmp[NN];
  __shared__ int cov[NN];
  __shared__ int dly[NN];
  __shared__ int mis_s[NN];
  __shared__ int row_ptr_s[NN + 1];
  __shared__ int col_ptr_s[NN + 1];
  __shared__ int cnt;
  int t = threadIdx.x;
  const uint4* col4 = (const uint4*)colidx;  // 8 u16 per uint4
  const uint4* row4 = (const uint4*)rowidx;

  for (int v = t; v < NN; v += 1024) {
    int rk = rank_g[v];
    rank_s[v] = rk;
    mr[v] = rk;
    tmp[v] = rk;
    cov[v] = 0;
    mis_s[v] = 0;
    row_ptr_s[v] = row_ptr_g[v];
    col_ptr_s[v] = col_ptr_g[v];
  }
  if (t == 0) {
    row_ptr_s[NN] = row_ptr_g[NN];
    col_ptr_s[NN] = col_ptr_g[NN];
    cnt = 0;
  }
  __syncthreads();

#define WALK_MIN()                                                          \
  for (int v = t; v < NN; v += 1024) {                                      \
    int val = tmp[v];                                                       \
    if (val != SEN) {                                                       \
      int e0 = row_ptr_s[v];                                                \
      int nch = (row_ptr_s[v + 1] - e0) >> 3;                               \
      const uint4* b4 = col4 + (e0 >> 3);                                   \
      for (int c = 0; c < nch; c += 2) {                                    \
        uint4 A = b4[c], B = b4[c + 1];                                     \
        atomicMin(&mr[A.x & 0xFFFFu], val); atomicMin(&mr[A.x >> 16], val); \
        atomicMin(&mr[A.y & 0xFFFFu], val); atomicMin(&mr[A.y >> 16], val); \
        atomicMin(&mr[A.z & 0xFFFFu], val); atomicMin(&mr[A.z >> 16], val); \
        atomicMin(&mr[A.w & 0xFFFFu], val); atomicMin(&mr[A.w >> 16], val); \
        atomicMin(&mr[B.x & 0xFFFFu], val); atomicMin(&mr[B.x >> 16], val); \
        atomicMin(&mr[B.y & 0xFFFFu], val); atomicMin(&mr[B.y >> 16], val); \
        atomicMin(&mr[B.z & 0xFFFFu], val); atomicMin(&mr[B.z >> 16], val); \
        atomicMin(&mr[B.w & 0xFFFFu], val); atomicMin(&mr[B.w >> 16], val); \
      }                                                                     \
    }                                                                       \
  }

#define WALK_OR()                                                           \
  for (int v = t; v < NN; v += 1024) {                                      \
    if (tmp[v]) {                                                           \
      int e0 = row_ptr_s[v];                                                \
      int nch = (row_ptr_s[v + 1] - e0) >> 3;                               \
      const uint4* b4 = col4 + (e0 >> 3);                                   \
      for (int c = 0; c < nch; c += 2) {                                    \
        uint4 A = b4[c], B = b4[c + 1];                                     \
        dly[A.x & 0xFFFFu] = 1; dly[A.x >> 16] = 1;                         \
        dly[A.y & 0xFFFFu] = 1; dly[A.y >> 16] = 1;                         \
        dly[A.z & 0xFFFFu] = 1; dly[A.z >> 16] = 1;                         \
        dly[A.w & 0xFFFFu] = 1; dly[A.w >> 16] = 1;                         \
        dly[B.x & 0xFFFFu] = 1; dly[B.x >> 16] = 1;                         \
        dly[B.y & 0xFFFFu] = 1; dly[B.y >> 16] = 1;                         \
        dly[B.z & 0xFFFFu] = 1; dly[B.z >> 16] = 1;                         \
        dly[B.w & 0xFFFFu] = 1; dly[B.w >> 16] = 1;                         \
      }                                                                     \
    }                                                                       \
  }

  for (int round = 0; round < NN; ++round) {
    // A: min hop0 — scatter from uncovered sources (tmp pre-snapshotted)
    WALK_MIN();
    __syncthreads();
    // B: snapshot
    for (int v = t; v < NN; v += 1024) tmp[v] = mr[v];
    __syncthreads();
    // C: min hop1 — gather at uncovered destinations via CSC
    for (int v = t; v < NN; v += 1024) {
      if (!cov[v]) {
        int val = tmp[v];
        int e0 = col_ptr_s[v];
        int nch = (col_ptr_s[v + 1] - e0) >> 3;
        const uint4* b4 = row4 + (e0 >> 3);
        for (int c = 0; c < nch; c += 2) {
          uint4 A = b4[c], B = b4[c + 1];
          int m0 = min(tmp[A.x & 0xFFFFu], tmp[A.x >> 16]);
          int m1 = min(tmp[A.y & 0xFFFFu], tmp[A.y >> 16]);
          int m2 = min(tmp[A.z & 0xFFFFu], tmp[A.z >> 16]);
          int m3 = min(tmp[A.w & 0xFFFFu], tmp[A.w >> 16]);
          int m4 = min(tmp[B.x & 0xFFFFu], tmp[B.x >> 16]);
          int m5 = min(tmp[B.y & 0xFFFFu], tmp[B.y >> 16]);
          int m6 = min(tmp[B.z & 0xFFFFu], tmp[B.z >> 16]);
          int m7 = min(tmp[B.w & 0xFFFFu], tmp[B.w >> 16]);
          val = min(val, min(min(min(m0, m1), min(m2, m3)),
                             min(min(m4, m5), min(m6, m7))));
        }
        mr[v] = val;
      }
    }
    __syncthreads();
    // D: delta = newly selected; mis |= delta
    for (int v = t; v < NN; v += 1024) {
      int nw = (rank_s[v] == mr[v]) ? 1 : 0;
      if (nw) mis_s[v] = 1;
      dly[v] = nw;
      tmp[v] = nw;
    }
    __syncthreads();
    // E: OR hop0 (delta-scoped scatter)
    WALK_OR();
    __syncthreads();
    // F: snapshot
    for (int v = t; v < NN; v += 1024) tmp[v] = dly[v];
    __syncthreads();
    // G: OR hop1
    WALK_OR();
    __syncthreads();
    // H: fold delta, reset mr, fused convergence
    int mypred = 0;
    for (int v = t; v < NN; v += 1024) {
      int cv = cov[v] | dly[v];
      cov[v] = cv;
      int nmr = cv ? SEN : rank_s[v];
      mr[v] = nmr;
      tmp[v] = nmr;
      mypred |= (cv == 0);
    }
    if (__syncthreads_count(mypred) == 0) break;
  }

  for (int v = t; v < NN; v += 1024) {
    int s = mis_s[v];
    mis_flag[v] = s;
    int slot = -1;
    if (s) {
      slot = atomicAdd(&cnt, 1);  // unordered: all consumers order-free
      mis_list[slot] = v;
    }
    misinv[v] = slot;
  }
  __syncthreads();
  if (t == 0) *mis_count = cnt;
}

// ---------------------------------------------------------------------------
// adj -> rw in place, fused with MIS-column gather into compact Bc.
// ---------------------------------------------------------------------------
__global__ __launch_bounds__(256) void rw_transform_gather(float* __restrict__ adj,
                                                           const float* __restrict__ rowsum,
                                                           const int* __restrict__ misinv,
                                                           float* __restrict__ Bc) {
  int idx = blockIdx.x * 256 + threadIdx.x;  // over N*N
  int i = idx >> 11, j = idx & (NN - 1);
  float s = rowsum[i];
  s = (s > 0.f) ? s : 1.f;
  float v = adj[idx] / s;
  v = (i == j) ? (v + EPSV) : (v * (1.f - EPSV));
  adj[idx] = v;
  int tc = misinv[j];
  if (tc >= 0) Bc[(size_t)tc * NN + i] = v;
}

// ---------------------------------------------------------------------------
// Fused c2 + Gumbel-argmax, 4 columns per job (round-8 structure).
// ---------------------------------------------------------------------------
__device__ inline unsigned int f32_key(float x) {
  unsigned int u = __float_as_uint(x);
  return (u & 0x80000000u) ? ~u : (u | 0x80000000u);
}
__device__ inline float dot4(float4 a, float4 b) {
  return ((a.x * b.x + a.y * b.y) + (a.z * b.z + a.w * b.w));
}
__device__ inline unsigned long long umax64(unsigned long long a, unsigned long long b) {
  return a > b ? a : b;
}

__global__ __launch_bounds__(256) void c2_argmax(const float* __restrict__ rw,
                                                 const float* __restrict__ Bc,
                                                 const float* __restrict__ u,
                                                 const int* __restrict__ mis_list,
                                                 const int* __restrict__ mis_count,
                                                 unsigned long long* __restrict__ packed) {
  int M = *mis_count;
  int ncg = (M + 3) >> 2;
  int njobs = ncg * 64;  // 64 tiles of 32 rows
  int lane = threadIdx.x & 63, w = threadIdx.x >> 6;
  for (int j = blockIdx.x; j < njobs; j += gridDim.x) {
    int cg = j >> 6, tile = j & 63;
    int c0 = cg * 4;
    float4 creg[4][8];
    int mcol[4];
#pragma unroll
    for (int cc = 0; cc < 4; ++cc) {
      int colv = c0 + cc;
      int cl = colv < M ? colv : (M - 1);
      mcol[cc] = mis_list[cl];
      const float4* cb = (const float4*)(Bc + (size_t)cl * NN);
#pragma unroll
      for (int q = 0; q < 8; ++q) creg[cc][q] = cb[q * 64 + lane];
    }
    int rbase = tile * 32 + w * 8;
#pragma unroll
    for (int it = 0; it < 8; ++it) {
      int r = rbase + it;
      const float4* rp = (const float4*)(rw + (size_t)r * NN);
      float4 a0 = rp[lane], a1 = rp[64 + lane], a2 = rp[128 + lane], a3 = rp[192 + lane];
      float4 a4 = rp[256 + lane], a5 = rp[320 + lane], a6 = rp[384 + lane], a7 = rp[448 + lane];
      float sacc[4];
#pragma unroll
      for (int cc = 0; cc < 4; ++cc) {
        float s01 = dot4(a0, creg[cc][0]) + dot4(a1, creg[cc][1]);
        float s23 = dot4(a2, creg[cc][2]) + dot4(a3, creg[cc][3]);
        float s45 = dot4(a4, creg[cc][4]) + dot4(a5, creg[cc][5]);
        float s67 = dot4(a6, creg[cc][6]) + dot4(a7, creg[cc][7]);
        float s = (s01 + s23) + (s45 + s67);
        s += __shfl_xor(s, 32);
        s += __shfl_xor(s, 16);
        s += __shfl_xor(s, 8);
        s += __shfl_xor(s, 4);
        s += __shfl_xor(s, 2);
        s += __shfl_xor(s, 1);
        sacc[cc] = s;
      }
      if (lane == 0) {
        unsigned long long best = 0ull;
#pragma unroll
        for (int cc = 0; cc < 4; ++cc) {
          if (c0 + cc < M && sacc[cc] > 0.f) {
            int m = mcol[cc];
            float uu = u[(size_t)r * NN + m];
            float g = -logf(-logf(uu + 1e-20f) + 1e-20f);
            float logit = logf(sacc[cc]) + g;
            unsigned long long key =
                ((unsigned long long)f32_key(logit) << 32) | (unsigned int)(NN - 1 - m);
            best = umax64(best, key);
          }
        }
        if (best) atomicMax(&packed[r], best);
      }
    }
  }
}

// ---------------------------------------------------------------------------
__global__ __launch_bounds__(256) void cluster_decode(const unsigned long long* __restrict__ packed,
                                                      int* __restrict__ cluster,
                                                      int* __restrict__ counts) {
  int i = blockIdx.x * 256 + threadIdx.x;
  unsigned long long p = packed[i];
  int m = (p == 0ull) ? 0 : (NN - 1 - (int)(p & 0xFFFFFFFFull));
  cluster[i] = m;
  atomicAdd(&counts[m], 1);
}

// ---------------------------------------------------------------------------
// Fused adj_c edge scatter + x_pool scatter (one dispatch).
// ---------------------------------------------------------------------------
__global__ __launch_bounds__(256) void scatter_fused(const int* __restrict__ row,
                                                     const int* __restrict__ col,
                                                     const float* __restrict__ attr,
                                                     const float* __restrict__ x,
                                                     const int* __restrict__ cluster,
                                                     float* __restrict__ adjc,
                                                     float* __restrict__ xp) {
  int idx = blockIdx.x * 256 + threadIdx.x;  // over N*D (= 1,048,576)
  if (idx < EE) {
    int cr = cluster[row[idx]], cc = cluster[col[idx]];
    atomicAdd(&adjc[(size_t)cr * NN + cc], attr[idx]);
  }
  int i = idx >> 9;
  atomicAdd(&xp[cluster[i] * DD + (idx & (DD - 1))], x[idx]);
}

// ---------------------------------------------------------------------------
// c_hard, p_inv, mis, and x_pool scaling in one pass.
// ---------------------------------------------------------------------------
__global__ __launch_bounds__(256) void write_chpm(const int* __restrict__ cluster,
                                                  const int* __restrict__ counts,
                                                  const int* __restrict__ mis_flag,
                                                  float* __restrict__ out_ch,
                                                  float* __restrict__ out_pinv,
                                                  float* __restrict__ out_mis,
                                                  float* __restrict__ out_xp) {
  int idx = blockIdx.x * 256 + threadIdx.x;  // over N*N
  int a = idx >> 11, b = idx & (NN - 1);
  out_ch[idx] = (cluster[a] == b) ? 1.f : 0.f;
  float pv = 0.f;
  if (cluster[b] == a) {
    int c = counts[a];
    pv = 1.f / (float)(c > 0 ? c : 1);
  }
  out_pinv[idx] = pv;
  if (idx < NN) out_mis[idx] = mis_flag[idx] ? 1.f : 0.f;
  if (idx < NN * DD) {
    int c = counts[idx >> 9];
    out_xp[idx] = out_xp[idx] / (float)(c > 0 ? c : 1);
  }
}

// ---------------------------------------------------------------------------
extern "C" void kernel_launch(void* const* d_in, const int* in_sizes, int n_in,
                              void* d_out, int out_size, void* d_ws, size_t ws_size,
                              hipStream_t stream) {
  const int*   edge_index = (const int*)d_in[0];
  const float* edge_attr  = (const float*)d_in[1];
  const float* x          = (const float*)d_in[2];
  const int*   rank       = (const int*)d_in[3];
  const float* u          = (const float*)d_in[4];
  float* out              = (float*)d_out;  // f32 outputs, concatenated

  const int* row = edge_index;
  const int* col = edge_index + EE;

  float* out_adjc = out;                 // N*N — doubles as adj/rw scratch
  float* out_ch   = out + SZ;            // N*N — doubles as Bc scratch
  float* out_pinv = out + 2 * SZ;        // N*N
  float* out_mis  = out + 3 * SZ;        // N
  float* out_xp   = out + 3 * SZ + NN;   // N*D

  // d_ws layout (~490 KB). First 5 arrays zeroed; rest fully written.
  unsigned long long* packed = (unsigned long long*)d_ws;  // N u64 (zeroed)
  float* rowsum    = (float*)(packed + NN);        // N  (zeroed)
  int*   counts    = (int*)(rowsum + NN);          // N  (zeroed)
  int*   degree    = counts + NN;                  // N  (zeroed)
  int*   cdeg      = degree + NN;                  // N  (zeroed)
  int*   mis_flag  = cdeg + NN;                    // N
  int*   cluster   = mis_flag + NN;                // N
  int*   mis_list  = cluster + NN;                 // N
  int*   misinv    = mis_list + NN;                // N
  int*   mis_count = misinv + NN;                  // 1
  int*   fill_ptr  = mis_count + 1;                // N
  int*   cfill_ptr = fill_ptr + NN;                // N
  int*   row_ptr   = cfill_ptr + NN;               // N+1
  int*   col_ptr   = row_ptr + NN + 1;             // N+1
  unsigned short* colidx =                          // padded E (<=98304) u16, 32B-aligned
      (unsigned short*)(((uintptr_t)(col_ptr + NN + 1) + 31) & ~(uintptr_t)31);
  unsigned short* rowidx = colidx + 98304;         // padded E u16 (32B-aligned: 98304*2%32==0)

  hipMemsetAsync(out_adjc, 0, SZ * sizeof(float), stream);
  hipMemsetAsync(out_xp, 0, (size_t)NN * DD * sizeof(float), stream);
  hipMemsetAsync(d_ws, 0, NN * sizeof(unsigned long long) + 4 * NN * sizeof(int), stream);

  build_adj<<<EE / 256, 256, 0, stream>>>(row, col, edge_attr, out_adjc, rowsum, degree, cdeg);
  csr_scan_pad<<<1, 1024, 0, stream>>>(degree, cdeg, row_ptr, fill_ptr, col_ptr, cfill_ptr,
                                       colidx, rowidx);
  csr_fill<<<EE / 256, 256, 0, stream>>>(row, col, fill_ptr, cfill_ptr, colidx, rowidx);
  mis_kernel<<<1, 1024, 0, stream>>>(row_ptr, col_ptr, colidx, rowidx, rank,
                                     mis_flag, mis_list, misinv, mis_count);
  rw_transform_gather<<<(NN * NN) / 256, 256, 0, stream>>>(out_adjc, rowsum, misinv, out_ch);
  c2_argmax<<<1024, 256, 0, stream>>>(out_adjc, out_ch, u, mis_list, mis_count, packed);
  cluster_decode<<<NN / 256, 256, 0, stream>>>(packed, cluster, counts);

  // rw no longer needed: rewrite the region with the real adj_c
  hipMemsetAsync(out_adjc, 0, SZ * sizeof(float), stream);
  scatter_fused<<<(NN * DD) / 256, 256, 0, stream>>>(row, col, edge_attr, x, cluster,
                                                     out_adjc, out_xp);

  write_chpm<<<(NN * NN) / 256, 256, 0, stream>>>(cluster, counts, mis_flag,
                                                  out_ch, out_pinv, out_mis, out_xp);
}